// Round 5
// baseline (3017.379 us; speedup 1.0000x reference)
//
#include <hip/hip_runtime.h>
#include <hip/hip_bf16.h>
#include <stdint.h>

// Chebyshev KAN: two layers of  out[b,o] = sum_{i,d} T_d(xhat[b,i]) * C[i,o,d]
// Round 9: DECOUPLE. Rounds 4-8 (fused producer, 600-700 TF) all hit the same
// wall: the in-loop Chebyshev producer keeps A on the critical path and blocks
// the proven m97 structure. Now:
//   1. kan_expand materializes A_cheb bf16 (T_1..T_8 per feature; T_0 folded
//      into bias) directly in GEMM-fragment tile order -> pure streaming write.
//   2. kan_gemm is an m97-clone: 128x128 tile, BK=32, both A and B staged via
//      global_load_lds (16B) from pre-tiled buffers, 2-buffer single-barrier
//      loop, 32 KB LDS, launch_bounds(256,3) -> 3 blocks/CU (m97: 874-912 TF).
//   3. M processed in chunks sized from ws_size (A-chunk buffer reused).
// k-order: k = feature*8 + (d-1). Tile layout (A and B identical structure):
//   addr(r|c, f_local, dhat) = (rl>>4)*1024 + f_local*256 + (rl&15)*16 + dhat*2
// which is exactly the frag order consumed by ds_read_b128 at lane*16
// (verified across rounds 4-8).

constexpr int BATCH   = 16384;
constexpr int IN_DIM  = 1024;
constexpr int HID_DIM = 2048;
constexpr int OUT_DIM = 1024;
#define DP1 9  // degree+1 (storage layout of input coeffs)

using bf16_t = __hip_bfloat16;

typedef __attribute__((ext_vector_type(4))) float f32x4;
typedef __attribute__((ext_vector_type(8))) short s16x8;
typedef __attribute__((ext_vector_type(8))) float f32x8;
typedef __attribute__((ext_vector_type(8))) __bf16 bf16x8;

static __device__ __forceinline__ unsigned int f2bf_u(float f) {
  union { __hip_bfloat16 h; unsigned short u; } cv;
  cv.h = __float2bfloat16(f);
  return (unsigned int)cv.u;
}

// ---------------- min/max over batch, per column (two stage) ----------------
template <typename T>
__global__ void kan_minmax_partial(const T* __restrict__ x, int rows, int cols,
                                   float* __restrict__ mnp, float* __restrict__ mxp) {
  const int c  = blockIdx.x * 64 + (threadIdx.x & 63);
  const int rg = threadIdx.x >> 6;
  const int P  = gridDim.y;
  const int chunk = rows / P;
  const int r0 = blockIdx.y * chunk;
  float mn = 1e30f, mx = -1e30f;
  for (int r = r0 + rg; r < r0 + chunk; r += 4) {
    float v = (float)x[(size_t)r * cols + c];
    mn = fminf(mn, v); mx = fmaxf(mx, v);
  }
  __shared__ float smn[256], smx[256];
  smn[threadIdx.x] = mn; smx[threadIdx.x] = mx;
  __syncthreads();
  if (rg == 0) {
    int t = threadIdx.x;
    mn = fminf(fminf(smn[t], smn[t + 64]), fminf(smn[t + 128], smn[t + 192]));
    mx = fmaxf(fmaxf(smx[t], smx[t + 64]), fmaxf(smx[t + 128], smx[t + 192]));
    mnp[(size_t)blockIdx.y * cols + c] = mn;
    mxp[(size_t)blockIdx.y * cols + c] = mx;
  }
}

__global__ void kan_minmax_finalize(const float* __restrict__ mnp, const float* __restrict__ mxp,
                                    int cols, int P, float* __restrict__ s, float* __restrict__ t) {
  int c = blockIdx.x * blockDim.x + threadIdx.x;
  if (c >= cols) return;
  float mn = 1e30f, mx = -1e30f;
  for (int p = 0; p < P; ++p) {
    mn = fminf(mn, mnp[(size_t)p * cols + c]);
    mx = fmaxf(mx, mxp[(size_t)p * cols + c]);
  }
  float inv = 2.0f / (mx - mn);
  s[c] = inv;
  t[c] = -mn * inv - 1.0f;
}

// ---- repack coeffs [I,O,9] fp32 -> Bt tiled bf16 (d=1..8) + bias partials ----
// Bt layout: [ntile = o/128][ktile = f/4][8 KB tile], tile addr as in header.
// Block = (ntile, ktile): covers o in [nt*128,+128), f in [kt*4,+4).
// d=0 -> biasp[kt*O + o] (LDS-reduced over the 4 features, deterministic).
__global__ void kan_repack(const float* __restrict__ coeffs, int I, int O,
                           bf16_t* __restrict__ Bt, float* __restrict__ biasp) {
  const int Ktiles = I / 4;
  const int kt = blockIdx.x % Ktiles;
  const int nt = blockIdx.x / Ktiles;
  __shared__ float sb[512];
  char* tile = reinterpret_cast<char*>(Bt) + ((size_t)nt * Ktiles + kt) * 8192;
#pragma unroll
  for (int pp = 0; pp < 2; ++pp) {
    const int p  = pp * 256 + threadIdx.x;
    const int ol = p & 127;
    const int fl = p >> 7;                     // 0..3
    const float* rp = coeffs + ((size_t)(kt * 4 + fl) * O + nt * 128 + ol) * DP1;
    float v[9];
#pragma unroll
    for (int d = 0; d < 9; ++d) v[d] = rp[d];
    sb[p] = v[0];
    unsigned int pk[4];
#pragma unroll
    for (int q = 0; q < 4; ++q)
      pk[q] = f2bf_u(v[2 * q + 1]) | (f2bf_u(v[2 * q + 2]) << 16);
    *reinterpret_cast<uint4*>(tile + (ol >> 4) * 1024 + fl * 256 + (ol & 15) * 16) =
        make_uint4(pk[0], pk[1], pk[2], pk[3]);
  }
  __syncthreads();
  if (threadIdx.x < 128) {
    const int ol = threadIdx.x;
    biasp[(size_t)kt * O + nt * 128 + ol] =
        sb[ol] + sb[ol + 128] + sb[ol + 256] + sb[ol + 384];
  }
}

__global__ void kan_bias_finalize(const float* __restrict__ biasp, int Ktiles, int O,
                                  float* __restrict__ bias) {
  const int o = blockIdx.x * blockDim.x + threadIdx.x;
  if (o >= O) return;
  float s = 0.f;
  for (int p = 0; p < Ktiles; ++p) s += biasp[(size_t)p * O + o];
  bias[o] = s;
}

// ---- expand: X rows [r0, r0+cm) -> At tiled bf16 Chebyshev ----
// grid (cm/256, I/4); thread = one row r_local, one 4-feature group kt.
// Writes one uint4 (T_1..T_8 bf16) per feature at tile-frag address.
template <typename AT>
__global__ void kan_expand(const AT* __restrict__ X, const float* __restrict__ sc,
                           const float* __restrict__ tc, bf16_t* __restrict__ At,
                           int I, int r0) {
  const int Ktiles = I / 4;
  const int rl = blockIdx.x * 256 + threadIdx.x;   // local row in chunk
  const int kt = blockIdx.y;
  const int f0 = kt * 4;
  float xv[4];
  if constexpr (sizeof(AT) == 4) {
    float4 v = *reinterpret_cast<const float4*>(X + (size_t)(r0 + rl) * I + f0);
    xv[0] = v.x; xv[1] = v.y; xv[2] = v.z; xv[3] = v.w;
  } else {
    uint2 v = *reinterpret_cast<const uint2*>(
        reinterpret_cast<const char*>(X) + ((size_t)(r0 + rl) * I + f0) * 2);
    xv[0] = __uint_as_float(v.x << 16);
    xv[1] = __uint_as_float(v.x & 0xffff0000u);
    xv[2] = __uint_as_float(v.y << 16);
    xv[3] = __uint_as_float(v.y & 0xffff0000u);
  }
  char* tile = reinterpret_cast<char*>(At) +
               ((size_t)(rl >> 7) * Ktiles + kt) * 8192 +
               ((rl & 127) >> 4) * 1024 + (rl & 15) * 16;
#pragma unroll
  for (int q = 0; q < 4; ++q) {
    const float xh = fmaf(xv[q], sc[f0 + q], tc[f0 + q]);
    f32x8 T;
    float tm2 = 1.0f, tm1 = xh;
    T[0] = xh;
#pragma unroll
    for (int d = 1; d < 8; ++d) {
      float t = 2.0f * xh * tm1 - tm2;
      tm2 = tm1; tm1 = t;
      T[d] = t;
    }
    union { bf16x8 v; uint4 u; } cv;
    cv.v = __builtin_convertvector(T, bf16x8);
    *reinterpret_cast<uint4*>(tile + q * 256) = cv.u;
  }
}

// ---------------- m97-clone bf16 GEMM on pre-tiled operands ----------------
// 128x128 block tile, 4 waves 2x2, wave tile 64x64 (acc 4x4 = 64 AGPR).
// BK=32; A,B each 8 KB/stage staged by global_load_lds width 16 from
// fragment-linear tiles; 2-buffer single-barrier loop; 32 KB LDS.
template <typename OT>
__launch_bounds__(256, 3)
__global__ void kan_gemm(const bf16_t* __restrict__ At, const bf16_t* __restrict__ Bt,
                         const float* __restrict__ bias, OT* __restrict__ out,
                         int Ktiles, int N, int m_off) {
  __shared__ __align__(16) short Als[2][4096];   // 2x8 KB
  __shared__ __align__(16) short Bls[2][4096];   // 2x8 KB

  const int tid  = threadIdx.x;
  const int lane = tid & 63;
  const int wave = tid >> 6;
  const int wr   = wave >> 1;
  const int wc   = wave & 1;
  const int quad = lane >> 4;
  const int l16  = lane & 15;

  const char* ga0 = reinterpret_cast<const char*>(At) +
                    (size_t)blockIdx.x * Ktiles * 8192 + wave * 1024 + lane * 16;
  const char* gb0 = reinterpret_cast<const char*>(Bt) +
                    (size_t)blockIdx.y * Ktiles * 8192 + wave * 1024 + lane * 16;

  auto dma = [&](int s) {
    const int b = s & 1;
    const char* ga = ga0 + (size_t)s * 8192;
    const char* gb = gb0 + (size_t)s * 8192;
    char* la = reinterpret_cast<char*>(&Als[b][0]) + wave * 1024;
    char* lb = reinterpret_cast<char*>(&Bls[b][0]) + wave * 1024;
#pragma unroll
    for (int t = 0; t < 2; ++t) {
      __builtin_amdgcn_global_load_lds(
          (const __attribute__((address_space(1))) void*)(ga + t * 4096),
          (__attribute__((address_space(3))) void*)(la + t * 4096), 16, 0, 0);
      __builtin_amdgcn_global_load_lds(
          (const __attribute__((address_space(1))) void*)(gb + t * 4096),
          (__attribute__((address_space(3))) void*)(lb + t * 4096), 16, 0, 0);
    }
  };

  f32x4 acc[4][4] = {};

  dma(0);
  __syncthreads();

  for (int s = 0; s < Ktiles; ++s) {
    if (s + 1 < Ktiles) dma(s + 1);

    const char* Ab = reinterpret_cast<const char*>(&Als[s & 1][0]) + lane * 16;
    const char* Bb = reinterpret_cast<const char*>(&Bls[s & 1][0]) + lane * 16;
    s16x8 fa[4], fb[4];
#pragma unroll
    for (int mt = 0; mt < 4; ++mt)
      fa[mt] = *reinterpret_cast<const s16x8*>(Ab + (wr * 4 + mt) * 1024);
#pragma unroll
    for (int nt = 0; nt < 4; ++nt)
      fb[nt] = *reinterpret_cast<const s16x8*>(Bb + (wc * 4 + nt) * 1024);

#pragma unroll
    for (int mt = 0; mt < 4; ++mt)
#pragma unroll
      for (int nt = 0; nt < 4; ++nt)
        acc[mt][nt] = __builtin_amdgcn_mfma_f32_16x16x32_bf16(
            fa[mt], fb[nt], acc[mt][nt], 0, 0, 0);

    __syncthreads();
  }

  // epilogue: C/D col = l16 (n), row = quad*4 + r (m); add bias
  const int n0 = blockIdx.y * 128 + wc * 64;
  const int m0 = m_off + blockIdx.x * 128 + wr * 64;
  float bv[4];
#pragma unroll
  for (int nt = 0; nt < 4; ++nt) bv[nt] = bias[n0 + nt * 16 + l16];
#pragma unroll
  for (int mt = 0; mt < 4; ++mt) {
#pragma unroll
    for (int nt = 0; nt < 4; ++nt) {
      const int n = n0 + nt * 16 + l16;
#pragma unroll
      for (int r = 0; r < 4; ++r) {
        const int m = m0 + mt * 16 + quad * 4 + r;
        float v = acc[mt][nt][r] + bv[nt];
        if constexpr (sizeof(OT) == 4)
          out[(size_t)m * N + n] = v;
        else
          out[(size_t)m * N + n] = __float2bfloat16(v);
      }
    }
  }
}

// ---------------- launcher ----------------
extern "C" void kernel_launch(void* const* d_in, const int* in_sizes, int n_in,
                              void* d_out, int out_size, void* d_ws, size_t ws_size,
                              hipStream_t stream) {
  const float* x  = (const float*)d_in[0];
  const float* c1 = (const float*)d_in[1];
  const float* c2 = (const float*)d_in[2];
  float* out = (float*)d_out;

  char* ws = (char*)d_ws;
  size_t off = 0;
  auto take = [&](size_t n) -> char* {
    char* p = ws + off;
    off += (n + 255) & ~(size_t)255;
    return p;
  };
  const int KT1 = IN_DIM / 4;    // 256 k-tiles (K1 = 8192)
  const int KT2 = HID_DIM / 4;   // 512 k-tiles (K2 = 16384)

  bf16_t* Bt1 = (bf16_t*)take((size_t)(HID_DIM / 128) * KT1 * 8192);  // 33.5 MB
  bf16_t* Bt2 = (bf16_t*)take((size_t)(OUT_DIM / 128) * KT2 * 8192);  // 33.5 MB
  bf16_t* h   = (bf16_t*)take((size_t)BATCH * HID_DIM * 2);           // 67 MB
  float* s1  = (float*)take(IN_DIM  * 4);
  float* t1  = (float*)take(IN_DIM  * 4);
  float* s2  = (float*)take(HID_DIM * 4);
  float* t2  = (float*)take(HID_DIM * 4);
  float* b1  = (float*)take(HID_DIM * 4);
  float* b2  = (float*)take(OUT_DIM * 4);
  float* bp1 = (float*)take((size_t)KT1 * HID_DIM * 4);               // 2 MB
  float* bp2 = (float*)take((size_t)KT2 * OUT_DIM * 4);               // 2 MB
  float* mnp = (float*)take((size_t)16 * HID_DIM * 4);
  float* mxp = (float*)take((size_t)16 * HID_DIM * 4);

  // A-chunk buffer: cm rows x K2(=16384) bf16, reused by both layers.
  size_t fixed = off;
  int cm = 1024;
  for (int c : {8192, 4096, 2048}) {
    if (fixed + (size_t)c * 16384 * 2 <= ws_size) { cm = c; break; }
  }
  bf16_t* A = (bf16_t*)take((size_t)cm * 16384 * 2);

  // normalization + repack (independent of chunks)
  kan_minmax_partial<float><<<dim3(IN_DIM / 64, 16), 256, 0, stream>>>(x, BATCH, IN_DIM, mnp, mxp);
  kan_minmax_finalize<<<dim3(IN_DIM / 256), 256, 0, stream>>>(mnp, mxp, IN_DIM, 16, s1, t1);
  kan_repack<<<dim3((HID_DIM / 128) * KT1), 256, 0, stream>>>(c1, IN_DIM, HID_DIM, Bt1, bp1);
  kan_bias_finalize<<<dim3(HID_DIM / 256), 256, 0, stream>>>(bp1, KT1, HID_DIM, b1);
  kan_repack<<<dim3((OUT_DIM / 128) * KT2), 256, 0, stream>>>(c2, HID_DIM, OUT_DIM, Bt2, bp2);
  kan_bias_finalize<<<dim3(OUT_DIM / 256), 256, 0, stream>>>(bp2, KT2, OUT_DIM, b2);

  // layer 1: expand + GEMM per chunk
  for (int r0 = 0; r0 < BATCH; r0 += cm) {
    kan_expand<float><<<dim3(cm / 256, KT1), 256, 0, stream>>>(x, s1, t1, A, IN_DIM, r0);
    kan_gemm<bf16_t><<<dim3(cm / 128, HID_DIM / 128), 256, 0, stream>>>(
        A, Bt1, b1, h, KT1, HID_DIM, r0);
  }

  // layer 2 normalization
  kan_minmax_partial<bf16_t><<<dim3(HID_DIM / 64, 16), 256, 0, stream>>>(h, BATCH, HID_DIM, mnp, mxp);
  kan_minmax_finalize<<<dim3(HID_DIM / 256), 256, 0, stream>>>(mnp, mxp, HID_DIM, 16, s2, t2);

  // layer 2: expand + GEMM per chunk
  for (int r0 = 0; r0 < BATCH; r0 += cm) {
    kan_expand<bf16_t><<<dim3(cm / 256, KT2), 256, 0, stream>>>(h, s2, t2, A, HID_DIM, r0);
    kan_gemm<float><<<dim3(cm / 128, OUT_DIM / 128), 256, 0, stream>>>(
        A, Bt2, b2, out, KT2, OUT_DIM, r0);
  }
}